// Round 9
// baseline (259.224 us; speedup 1.0000x reference)
//
#include <hip/hip_runtime.h>
#include <hip/hip_bf16.h>
#include <hip/hip_cooperative_groups.h>

namespace cg = cooperative_groups;

typedef __attribute__((ext_vector_type(8))) short short8;
typedef __attribute__((ext_vector_type(4))) float f32x4;

#define LDW 40   // conv LDS row pitch in ushorts (80 B)

__device__ __forceinline__ unsigned short f2bf(float f) {
  __hip_bfloat16 h = __float2bfloat16(f);
  return *(unsigned short*)&h;
}
__device__ __forceinline__ float bf2f(unsigned h) {
  return __uint_as_float(h << 16);
}
__device__ __forceinline__ unsigned pk2(float a, float b) {
  return (unsigned)f2bf(a) | ((unsigned)f2bf(b) << 16);
}
__device__ __forceinline__ unsigned long long pack4(float a, float b, float c, float d) {
  return (unsigned long long)pk2(a, b) | ((unsigned long long)pk2(c, d) << 32);
}

// Single cooperative kernel: phase0 (zero + w->bf16) | conv+bnstats | encode | gscale
// 512 blocks x 256 threads; 2 blocks/CU (LDS 55.4KB/block). Registers carry the
// conv output tile across the BN grid.sync -> y never goes to global memory.
__global__ __launch_bounds__(256, 2) void fused(
    const float* __restrict__ x, const float* __restrict__ conv_w,
    const float* __restrict__ conv_b, const float* __restrict__ bn_g,
    const float* __restrict__ bn_b, const float* __restrict__ cw,
    const float* __restrict__ scale, const float* __restrict__ lin_w,
    const float* __restrict__ lin_b, float* __restrict__ out,
    unsigned short* __restrict__ w_bf, float* __restrict__ S0,
    float* __restrict__ bn_acc, float* __restrict__ e_acc) {
  __shared__ __align__(16) unsigned char smem[55424];
  const int blk = blockIdx.x;
  const int tid = threadIdx.x;
  const int lane = tid & 63, wv = tid >> 6;
  const int li = lane & 15, q = lane >> 4;
  const int b = blk >> 5, nb = blk & 31;
  const int n0 = nb * 128;
  cg::grid_group grid = cg::this_grid();

  // ---------------- phase 0: zero accumulators, convert W to bf16
  if (tid < 64) e_acc[blk * 64 + tid] = 0.f;
  if (blk == 0) { S0[tid] = 0.f; bn_acc[tid] = 0.f; }
  if (tid < 32) {
    int i = blk * 32 + tid;
    float4 v = ((const float4*)conv_w)[i];
    *(unsigned long long*)(w_bf + 4 * i) = pack4(v.x, v.y, v.z, v.w);
  }
  grid.sync();

  // ---------------- phase A: conv (bf16 MFMA), acc kept in registers
  unsigned short* Wl = (unsigned short*)smem;            // [128][LDW]
  unsigned short* Xl = (unsigned short*)(smem + 10240);  // [128][LDW]
  f32x4 acc[2][8];
#pragma unroll
  for (int m = 0; m < 2; ++m)
#pragma unroll
    for (int r = 0; r < 8; ++r) acc[m][r] = (f32x4){0.f, 0.f, 0.f, 0.f};
  {
    const float* xb = x + (size_t)b * (512 * 4096) + n0;
    const int nq = tid & 31, cgp = tid >> 5;
    for (int c0 = 0; c0 < 512; c0 += 32) {
#pragma unroll
      for (int i = 0; i < 2; ++i) {
        int idx = tid + i * 256;
        int d = idx >> 2, hh = idx & 3;
        *(short8*)&Wl[d * LDW + hh * 8] = *(const short8*)(w_bf + (size_t)d * 512 + c0 + hh * 8);
      }
      {
        const float* xp = xb + (size_t)(c0 + cgp * 4) * 4096 + nq * 4;
        float4 v0 = *(const float4*)(xp);
        float4 v1 = *(const float4*)(xp + 4096);
        float4 v2 = *(const float4*)(xp + 2 * 4096);
        float4 v3 = *(const float4*)(xp + 3 * 4096);
        const float* a0 = (const float*)&v0;
        const float* a1 = (const float*)&v1;
        const float* a2 = (const float*)&v2;
        const float* a3 = (const float*)&v3;
#pragma unroll
        for (int j = 0; j < 4; ++j) {
          *(unsigned long long*)&Xl[(nq * 4 + j) * LDW + cgp * 4] =
              pack4(a0[j], a1[j], a2[j], a3[j]);
        }
      }
      __syncthreads();
      short8 af[2], bfr[8];
#pragma unroll
      for (int m = 0; m < 2; ++m)
        af[m] = *(const short8*)&Xl[(32 * wv + 16 * m + li) * LDW + q * 8];
#pragma unroll
      for (int r = 0; r < 8; ++r)
        bfr[r] = *(const short8*)&Wl[(16 * r + li) * LDW + q * 8];
#pragma unroll
      for (int m = 0; m < 2; ++m)
#pragma unroll
        for (int r = 0; r < 8; ++r)
          acc[m][r] = __builtin_amdgcn_mfma_f32_16x16x32_bf16(af[m], bfr[r], acc[m][r], 0, 0, 0);
      __syncthreads();
    }
  }
  // bias add (in place) + BN partial stats
  {
    float s1[8], s2[8];
#pragma unroll
    for (int rr = 0; rr < 8; ++rr) { s1[rr] = 0.f; s2[rr] = 0.f; }
#pragma unroll
    for (int rr = 0; rr < 8; ++rr) {
      int d = 16 * rr + li;
      float bb = conv_b[d];
#pragma unroll
      for (int m = 0; m < 2; ++m)
#pragma unroll
        for (int r = 0; r < 4; ++r) {
          float v = acc[m][rr][r] + bb;
          acc[m][rr][r] = v;
          s1[rr] += v;
          s2[rr] += v * v;
        }
    }
#pragma unroll
    for (int rr = 0; rr < 8; ++rr) {
      s1[rr] += __shfl_xor(s1[rr], 16); s1[rr] += __shfl_xor(s1[rr], 32);
      s2[rr] += __shfl_xor(s2[rr], 16); s2[rr] += __shfl_xor(s2[rr], 32);
    }
    float* red = (float*)smem;   // 1024 floats over dead Wl
    if (lane < 16) {
#pragma unroll
      for (int rr = 0; rr < 8; ++rr) {
        red[0 * 512 + wv * 128 + rr * 16 + li] = s1[rr];
        red[1 * 512 + wv * 128 + rr * 16 + li] = s2[rr];
      }
    }
    __syncthreads();
    {
      int s = tid >> 7, d = tid & 127;
      float v = red[s * 512 + d] + red[s * 512 + 128 + d]
              + red[s * 512 + 256 + d] + red[s * 512 + 384 + d];
      atomicAdd(&bn_acc[s * 128 + d], v);
    }
  }
  grid.sync();

  // ---------------- phase B: encode (BN+ReLU from registers -> Xt, softmax, MFMA)
  unsigned short* Xt = (unsigned short*)smem;            // [128 d][128 tok], ^((d&7)<<3)
  unsigned short* Pt = (unsigned short*)(smem + 32768);  // [16 k][128 tok], ^((k&7)<<3)
  float* cws    = (float*)(smem + 36864);                // [16][128]
  float* comb   = (float*)(smem + 45056);                // [128][17]
  float* scs    = (float*)(smem + 53760);
  float* shs    = (float*)(smem + 54272);
  float* c2s    = (float*)(smem + 54784);
  float* sscale = (float*)(smem + 54848);
  for (int i = tid; i < 2048; i += 256) cws[i] = cw[i];
  if (tid < 128) {
    float mu = bn_acc[tid] * (1.f / 65536.f);
    float var = bn_acc[128 + tid] * (1.f / 65536.f) - mu * mu;
    float sc = rsqrtf(var + 1e-5f) * bn_g[tid];
    scs[tid] = sc;
    shs[tid] = bn_b[tid] - mu * sc;
  }
  if (tid < 16) sscale[tid] = scale[tid];
  __syncthreads();
  if (tid < 16) {
    float s = 0.f;
#pragma unroll
    for (int d = 0; d < 128; ++d) s += cws[tid * 128 + d] * cws[tid * 128 + d];
    c2s[tid] = s;
  }
  // register tile -> Xt (BN + ReLU + bf16 pack)
#pragma unroll
  for (int rr = 0; rr < 8; ++rr) {
    int d = 16 * rr + li;
    float sc = scs[d], sh = shs[d];
#pragma unroll
    for (int m = 0; m < 2; ++m) {
      int nl = 32 * wv + 16 * m + 4 * q;
      float xv0 = fmaxf(fmaf(acc[m][rr][0], sc, sh), 0.f);
      float xv1 = fmaxf(fmaf(acc[m][rr][1], sc, sh), 0.f);
      float xv2 = fmaxf(fmaf(acc[m][rr][2], sc, sh), 0.f);
      float xv3 = fmaxf(fmaf(acc[m][rr][3], sc, sh), 0.f);
      *(unsigned long long*)&Xt[(d * 128 + nl) ^ ((d & 7) << 3)] =
          pack4(xv0, xv1, xv2, xv3);
    }
  }
  __syncthreads();
  // distances: token t = tid&127, d-half h = tid>>7
  {
    const int t = tid & 127, h = tid >> 7;
    const int dbase = h * 64;
    float dot[16];
#pragma unroll
    for (int k = 0; k < 16; ++k) dot[k] = 0.f;
    float x2 = 0.f;
    for (int dd = 0; dd < 64; dd += 4) {
      float xv[4];
#pragma unroll
      for (int j = 0; j < 4; ++j) {
        int d = dbase + dd + j;
        float v = bf2f(Xt[(d * 128 + t) ^ ((d & 7) << 3)]);
        xv[j] = v;
        x2 = fmaf(v, v, x2);
      }
#pragma unroll
      for (int k = 0; k < 16; ++k) {
        const float4 cv = *(const float4*)&cws[k * 128 + dbase + dd];
        dot[k] += xv[0] * cv.x + xv[1] * cv.y + xv[2] * cv.z + xv[3] * cv.w;
      }
    }
    if (h == 1) {
#pragma unroll
      for (int k = 0; k < 16; ++k) comb[t * 17 + k] = dot[k];
      comb[t * 17 + 16] = x2;
    }
    __syncthreads();
    if (h == 0) {
#pragma unroll
      for (int k = 0; k < 16; ++k) dot[k] += comb[t * 17 + k];
      x2 += comb[t * 17 + 16];
      float mx = -1e30f, sl[16];
#pragma unroll
      for (int k = 0; k < 16; ++k) {
        sl[k] = sscale[k] * (x2 + c2s[k] - 2.f * dot[k]);
        mx = fmaxf(mx, sl[k]);
      }
      float s = 0.f, p[16];
#pragma unroll
      for (int k = 0; k < 16; ++k) { p[k] = __expf(sl[k] - mx); s += p[k]; }
      float inv = 1.f / s;
#pragma unroll
      for (int k = 0; k < 16; ++k) {
        p[k] *= inv;
        Pt[(k * 128 + t) ^ ((k & 7) << 3)] = f2bf(p[k]);
      }
#pragma unroll
      for (int k = 0; k < 16; ++k) {
        float v = p[k];
#pragma unroll
        for (int off = 32; off; off >>= 1) v += __shfl_xor(v, off);
        if (lane == 0) atomicAdd(&S0[b * 16 + k], v);
      }
    }
    __syncthreads();
  }
  // E[k][d] += P^T X via MFMA: 4 waves x 2 d-tiles
  {
    f32x4 eacc[2];
    eacc[0] = (f32x4){0.f, 0.f, 0.f, 0.f};
    eacc[1] = (f32x4){0.f, 0.f, 0.f, 0.f};
#pragma unroll
    for (int ks = 0; ks < 4; ++ks) {
      int t0 = ks * 32 + q * 8;
      short8 af = *(const short8*)&Pt[(li * 128 + t0) ^ ((li & 7) << 3)];
#pragma unroll
      for (int j = 0; j < 2; ++j) {
        int d = (wv * 2 + j) * 16 + li;
        short8 bfv = *(const short8*)&Xt[(d * 128 + t0) ^ ((d & 7) << 3)];
        eacc[j] = __builtin_amdgcn_mfma_f32_16x16x32_bf16(af, bfv, eacc[j], 0, 0, 0);
      }
    }
    float* eb = e_acc + (size_t)b * 2048;
#pragma unroll
    for (int j = 0; j < 2; ++j) {
      int d = (wv * 2 + j) * 16 + li;
#pragma unroll
      for (int r = 0; r < 4; ++r)
        atomicAdd(&eb[(q * 4 + r) * 128 + d], eacc[j][r]);
    }
  }
  grid.sync();

  // ---------------- phase C: gscale (e = e_acc - S0*cw, ||e||, gates, out = x*gate)
  {
    float* es     = (float*)smem;            // 2048 floats
    float* sred   = (float*)(smem + 8192);   // 256
    float* gs     = (float*)(smem + 9216);   // 16
    float* s_invp = (float*)(smem + 9280);   // 1
    const float* eb = e_acc + (size_t)b * 2048;
    float ss = 0.f;
    for (int i = tid; i < 512; i += 256) {
      float4 v = ((const float4*)eb)[i];
      int k = i >> 5;
      int dbase2 = (i * 4) & 127;
      float s0k = S0[b * 16 + k];
      const float4 cv = *(const float4*)(cw + k * 128 + dbase2);
      v.x -= s0k * cv.x; v.y -= s0k * cv.y; v.z -= s0k * cv.z; v.w -= s0k * cv.w;
      *(float4*)&es[i * 4] = v;
      ss += v.x * v.x + v.y * v.y + v.z * v.z + v.w * v.w;
    }
    sred[tid] = ss;
    __syncthreads();
    for (int off = 128; off; off >>= 1) {
      if (tid < off) sred[tid] += sred[tid + off];
      __syncthreads();
    }
    if (tid == 0) s_invp[0] = 1.f / fmaxf(sqrtf(sred[0]), 1e-12f);
    __syncthreads();
#pragma unroll
    for (int i = 0; i < 4; ++i) {
      int ch = wv * 4 + i;
      int c = nb * 16 + ch;
      const float* wr = lin_w + (size_t)c * 2048;
      float dotv = 0.f;
#pragma unroll
      for (int j = 0; j < 8; ++j) {
        int idx = j * 64 + lane;
        float4 wvv = ((const float4*)wr)[idx];
        const float* ep = &es[idx * 4];
        dotv += wvv.x * ep[0] + wvv.y * ep[1] + wvv.z * ep[2] + wvv.w * ep[3];
      }
#pragma unroll
      for (int off = 32; off; off >>= 1) dotv += __shfl_xor(dotv, off);
      if (lane == 0) {
        float z = dotv * s_invp[0] + lin_b[c];
        gs[ch] = 1.f / (1.f + __expf(-z));
      }
    }
    __syncthreads();
    const float* xb2 = x + ((size_t)b * 512 + nb * 16) * 4096;
    float* ob = out + ((size_t)b * 512 + nb * 16) * 4096;
#pragma unroll 2
    for (int ch = 0; ch < 16; ++ch) {
      float g = gs[ch];
      const float4* xp = (const float4*)(xb2 + ch * 4096);
      float4* op = (float4*)(ob + ch * 4096);
      for (int i = tid; i < 1024; i += 256) {
        float4 v = xp[i];
        v.x *= g; v.y *= g; v.z *= g; v.w *= g;
        op[i] = v;
      }
    }
  }
}

extern "C" void kernel_launch(void* const* d_in, const int* in_sizes, int n_in,
                              void* d_out, int out_size, void* d_ws, size_t ws_size,
                              hipStream_t stream) {
  const float* x      = (const float*)d_in[0];
  const float* conv_w = (const float*)d_in[1];
  const float* conv_b = (const float*)d_in[2];
  const float* bn_g   = (const float*)d_in[3];
  const float* bn_b   = (const float*)d_in[4];
  const float* cw     = (const float*)d_in[5];
  const float* scale  = (const float*)d_in[6];
  const float* lin_w  = (const float*)d_in[7];
  const float* lin_b  = (const float*)d_in[8];
  float* out = (float*)d_out;
  float* ws  = (float*)d_ws;

  float* S0     = ws;                                   // 256
  float* bn_acc = ws + 256;                             // 256
  float* e_acc  = ws + 512;                             // 32768
  unsigned short* w_bf = (unsigned short*)(ws + 33280); // 65536 ushorts

  void* args[] = {(void*)&x, (void*)&conv_w, (void*)&conv_b, (void*)&bn_g,
                  (void*)&bn_b, (void*)&cw, (void*)&scale, (void*)&lin_w,
                  (void*)&lin_b, (void*)&out, (void*)&w_bf, (void*)&S0,
                  (void*)&bn_acc, (void*)&e_acc};
  hipLaunchCooperativeKernel((const void*)fused, dim3(512), dim3(256), args, 0, stream);
}

// Round 12
// 176.247 us; speedup vs baseline: 1.4708x; 1.4708x over previous
//
#include <hip/hip_runtime.h>
#include <hip/hip_bf16.h>

typedef __attribute__((ext_vector_type(8))) short short8;
typedef __attribute__((ext_vector_type(4))) float f32x4;

#define LDW2 72   // conv LDS row pitch in ushorts (144 B, 16B-aligned rows; bank stride 4)

__device__ __forceinline__ unsigned short f2bf(float f) {
  __hip_bfloat16 h = __float2bfloat16(f);
  return *(unsigned short*)&h;
}
__device__ __forceinline__ float bf2f(unsigned h) {
  return __uint_as_float(h << 16);
}
__device__ __forceinline__ unsigned pk2(float a, float b) {
  return (unsigned)f2bf(a) | ((unsigned)f2bf(b) << 16);
}
__device__ __forceinline__ unsigned long long pack4(float a, float b, float c, float d) {
  return (unsigned long long)pk2(a, b) | ((unsigned long long)pk2(c, d) << 32);
}

// ---------------- prep: w -> bf16, zero S0+bn_acc+e_acc
__global__ __launch_bounds__(256) void prep(const float* __restrict__ w,
    unsigned short* __restrict__ w_bf, float* __restrict__ S0, float* __restrict__ e_acc) {
  int i = blockIdx.x * 256 + threadIdx.x;
  float4 v = ((const float4*)w)[i];
  *(unsigned long long*)(w_bf + 4 * i) = pack4(v.x, v.y, v.z, v.w);
  e_acc[2 * i] = 0.f;
  e_acc[2 * i + 1] = 0.f;
  if (blockIdx.x == 0) {
    S0[threadIdx.x] = 0.f;
    S0[256 + threadIdx.x] = 0.f;
  }
}

// ---------------- Phase 1: conv bf16 MFMA. 64-token tiles, BK=64 (1024 blocks -> 4/CU).
__global__ __launch_bounds__(256) void conv_mfma(const float* __restrict__ x,
    const unsigned short* __restrict__ w_bf, const float* __restrict__ bias,
    unsigned short* __restrict__ y, float* __restrict__ bn_acc) {
  const int b = blockIdx.y;
  const int n0 = blockIdx.x * 64;
  const int tid = threadIdx.x;
  const int lane = tid & 63, wv = tid >> 6;
  const int li = lane & 15, q = lane >> 4;
  __shared__ unsigned short Wl[128 * LDW2];   // 18432 B
  __shared__ unsigned short Xl[64 * LDW2];    //  9216 B
  f32x4 acc[8];
#pragma unroll
  for (int r = 0; r < 8; ++r) acc[r] = (f32x4){0.f, 0.f, 0.f, 0.f};
  const float* xb = x + (size_t)b * (512 * 4096) + n0;
  const int nq = tid & 15, cgp = tid >> 4;   // 16 n-quads x 16 c-quads
  for (int c0 = 0; c0 < 512; c0 += 64) {
    // stage W[0..128)[c0..c0+64): 1024 short8 / 256 threads
#pragma unroll
    for (int i = 0; i < 4; ++i) {
      int idx = tid + i * 256;
      int d = idx >> 3, hh = idx & 7;
      *(short8*)&Wl[d * LDW2 + hh * 8] = *(const short8*)(w_bf + (size_t)d * 512 + c0 + hh * 8);
    }
    // stage X^T[n][c]: 4 float4 loads (4n x 4c), pack -> 4 b64 LDS writes
    {
      const float* xp = xb + (size_t)(c0 + cgp * 4) * 4096 + nq * 4;
      float4 v0 = *(const float4*)(xp);
      float4 v1 = *(const float4*)(xp + 4096);
      float4 v2 = *(const float4*)(xp + 2 * 4096);
      float4 v3 = *(const float4*)(xp + 3 * 4096);
      const float* a0 = (const float*)&v0;
      const float* a1 = (const float*)&v1;
      const float* a2 = (const float*)&v2;
      const float* a3 = (const float*)&v3;
#pragma unroll
      for (int j = 0; j < 4; ++j) {
        *(unsigned long long*)&Xl[(nq * 4 + j) * LDW2 + cgp * 4] =
            pack4(a0[j], a1[j], a2[j], a3[j]);
      }
    }
    __syncthreads();
#pragma unroll
    for (int kk = 0; kk < 2; ++kk) {
      short8 af = *(const short8*)&Xl[(wv * 16 + li) * LDW2 + kk * 32 + q * 8];
      short8 bfr[8];
#pragma unroll
      for (int r = 0; r < 8; ++r)
        bfr[r] = *(const short8*)&Wl[(16 * r + li) * LDW2 + kk * 32 + q * 8];
#pragma unroll
      for (int r = 0; r < 8; ++r)
        acc[r] = __builtin_amdgcn_mfma_f32_16x16x32_bf16(af, bfr[r], acc[r], 0, 0, 0);
    }
    __syncthreads();
  }
  // epilogue: wave wv owns tokens n0+wv*16+4q+reg, d = 16r+li
  float s1[8], s2[8];
#pragma unroll
  for (int r = 0; r < 8; ++r) { s1[r] = 0.f; s2[r] = 0.f; }
#pragma unroll
  for (int r = 0; r < 8; ++r) {
    int d = 16 * r + li;
    float bb = bias[d];
    float v0 = acc[r][0] + bb, v1 = acc[r][1] + bb;
    float v2 = acc[r][2] + bb, v3 = acc[r][3] + bb;
    s1[r] += v0 + v1 + v2 + v3;
    s2[r] += v0 * v0 + v1 * v1 + v2 * v2 + v3 * v3;
    *(unsigned long long*)(y + ((size_t)(b * 128 + d)) * 4096 + n0 + wv * 16 + 4 * q) =
        pack4(v0, v1, v2, v3);
  }
#pragma unroll
  for (int r = 0; r < 8; ++r) {
    s1[r] += __shfl_xor(s1[r], 16); s1[r] += __shfl_xor(s1[r], 32);
    s2[r] += __shfl_xor(s2[r], 16); s2[r] += __shfl_xor(s2[r], 32);
  }
  float* red = (float*)Wl;   // 1024 floats over dead Wl (all frag reads done pre-barrier)
  if (lane < 16) {
#pragma unroll
    for (int r = 0; r < 8; ++r) {
      red[0 * 512 + wv * 128 + r * 16 + li] = s1[r];
      red[1 * 512 + wv * 128 + r * 16 + li] = s2[r];
    }
  }
  __syncthreads();
  {
    int s = tid >> 7, d = tid & 127;
    float v = red[s * 512 + d] + red[s * 512 + 128 + d]
            + red[s * 512 + 256 + d] + red[s * 512 + 384 + d];
    atomicAdd(&bn_acc[s * 128 + d], v);
  }
}

// ---------------- Phase 2 (fused assign+aggregate): unchanged from round 8
__global__ __launch_bounds__(128) void encode(const unsigned short* __restrict__ y,
    const float* __restrict__ bn_acc, const float* __restrict__ bn_g,
    const float* __restrict__ bn_b, const float* __restrict__ cw,
    const float* __restrict__ scale, float* __restrict__ e_acc, float* __restrict__ S0) {
  const int b = blockIdx.y;
  const int n0 = blockIdx.x * 128;
  const int tid = threadIdx.x;          // 0..127
  const int lane = tid & 63, wv = tid >> 6;
  __shared__ unsigned short Xt[128 * 128];  // [d][tok] bf16, idx ^= (d&7)<<3
  __shared__ unsigned short Pt[16 * 128];   // [k][tok] bf16, idx ^= (k&7)<<3
  __shared__ float cws[16][128];
  __shared__ float c2s[16], scs[128], shs[128], sscale[16];
  for (int i = tid; i < 2048; i += 128) cws[i >> 7][i & 127] = cw[i];
  {
    float mu = bn_acc[tid] * (1.f / 65536.f);
    float var = bn_acc[128 + tid] * (1.f / 65536.f) - mu * mu;
    float sc = rsqrtf(var + 1e-5f) * bn_g[tid];
    scs[tid] = sc;
    shs[tid] = bn_b[tid] - mu * sc;
  }
  if (tid < 16) sscale[tid] = scale[tid];
  __syncthreads();
  if (tid < 16) {
    float s = 0.f;
#pragma unroll
    for (int d = 0; d < 128; ++d) s += cws[tid][d] * cws[tid][d];
    c2s[tid] = s;
  }
  __syncthreads();
  float dot0[16], dot1[16];
#pragma unroll
  for (int k = 0; k < 16; ++k) { dot0[k] = 0.f; dot1[k] = 0.f; }
  float x20 = 0.f, x21 = 0.f;
  const unsigned short* yb = y + (size_t)b * 524288 + n0 + 2 * tid;
  for (int d4 = 0; d4 < 128; d4 += 4) {
    float xv0[4], xv1[4];
#pragma unroll
    for (int j = 0; j < 4; ++j) {
      int d = d4 + j;
      unsigned pr = *(const unsigned*)(yb + (size_t)d * 4096);
      float sc = scs[d], sh = shs[d];
      float a0 = fmaxf(fmaf(bf2f(pr & 0xFFFFu), sc, sh), 0.f);
      float a1 = fmaxf(fmaf(bf2f(pr >> 16), sc, sh), 0.f);
      xv0[j] = a0; xv1[j] = a1;
      x20 = fmaf(a0, a0, x20); x21 = fmaf(a1, a1, x21);
      *(unsigned*)&Xt[(d * 128 + 2 * tid) ^ ((d & 7) << 3)] = pk2(a0, a1);
    }
#pragma unroll
    for (int k = 0; k < 16; ++k) {
      float4 cv = *(const float4*)&cws[k][d4];
      dot0[k] += xv0[0] * cv.x + xv0[1] * cv.y + xv0[2] * cv.z + xv0[3] * cv.w;
      dot1[k] += xv1[0] * cv.x + xv1[1] * cv.y + xv1[2] * cv.z + xv1[3] * cv.w;
    }
  }
  float p0[16], p1[16];
  {
    float m0 = -1e30f, m1 = -1e30f, sl0[16], sl1[16];
#pragma unroll
    for (int k = 0; k < 16; ++k) {
      sl0[k] = sscale[k] * (x20 + c2s[k] - 2.f * dot0[k]);
      sl1[k] = sscale[k] * (x21 + c2s[k] - 2.f * dot1[k]);
      m0 = fmaxf(m0, sl0[k]); m1 = fmaxf(m1, sl1[k]);
    }
    float s0 = 0.f, s1 = 0.f;
#pragma unroll
    for (int k = 0; k < 16; ++k) {
      p0[k] = __expf(sl0[k] - m0); s0 += p0[k];
      p1[k] = __expf(sl1[k] - m1); s1 += p1[k];
    }
    float i0 = 1.f / s0, i1 = 1.f / s1;
#pragma unroll
    for (int k = 0; k < 16; ++k) { p0[k] *= i0; p1[k] *= i1; }
  }
#pragma unroll
  for (int k = 0; k < 16; ++k)
    *(unsigned*)&Pt[(k * 128 + 2 * tid) ^ ((k & 7) << 3)] = pk2(p0[k], p1[k]);
#pragma unroll
  for (int k = 0; k < 16; ++k) {
    float v = p0[k] + p1[k];
#pragma unroll
    for (int off = 32; off; off >>= 1) v += __shfl_xor(v, off);
    if (lane == 0) atomicAdd(&S0[b * 16 + k], v);
  }
  __syncthreads();
  const int li = lane & 15, q = lane >> 4;
  f32x4 eacc[4];
#pragma unroll
  for (int dt = 0; dt < 4; ++dt) eacc[dt] = (f32x4){0.f, 0.f, 0.f, 0.f};
#pragma unroll
  for (int ks = 0; ks < 4; ++ks) {
    int t0 = ks * 32 + q * 8;
    short8 af = *(const short8*)&Pt[(li * 128 + t0) ^ ((li & 7) << 3)];
#pragma unroll
    for (int dt = 0; dt < 4; ++dt) {
      int d = (wv * 4 + dt) * 16 + li;
      short8 bf = *(const short8*)&Xt[(d * 128 + t0) ^ ((d & 7) << 3)];
      eacc[dt] = __builtin_amdgcn_mfma_f32_16x16x32_bf16(af, bf, eacc[dt], 0, 0, 0);
    }
  }
  float* eb = e_acc + (size_t)b * 2048;
#pragma unroll
  for (int dt = 0; dt < 4; ++dt) {
    int d = (wv * 4 + dt) * 16 + li;
#pragma unroll
    for (int r = 0; r < 4; ++r) {
      int k = q * 4 + r;
      atomicAdd(&eb[k * 128 + d], eacc[dt][r]);
    }
  }
}

// ---------------- Phase 3 (fused gate+scale, n-quarter split): 2048 blocks.
__global__ __launch_bounds__(256) void gscale(const float* __restrict__ e_acc,
    const float* __restrict__ S0, const float* __restrict__ cw,
    const float* __restrict__ lin_w, const float* __restrict__ lin_b,
    const float* __restrict__ x, float* __restrict__ out) {
  const int b = blockIdx.y;
  const int cb = blockIdx.x >> 2;     // 32 channel-groups of 16
  const int nq = blockIdx.x & 3;      // n-quarter
  const int tid = threadIdx.x;
  __shared__ float es[2048];
  __shared__ float sred[256];
  __shared__ float s_inv;
  __shared__ float gs[16];
  const float* eb = e_acc + (size_t)b * 2048;
  float ss = 0.f;
  for (int i = tid; i < 512; i += 256) {
    float4 v = ((const float4*)eb)[i];
    int k = i >> 5;
    int dbase = (i * 4) & 127;
    float s0k = S0[b * 16 + k];
    const float4 cv = *(const float4*)(cw + k * 128 + dbase);
    v.x -= s0k * cv.x; v.y -= s0k * cv.y; v.z -= s0k * cv.z; v.w -= s0k * cv.w;
    *(float4*)&es[i * 4] = v;
    ss += v.x * v.x + v.y * v.y + v.z * v.z + v.w * v.w;
  }
  sred[tid] = ss;
  __syncthreads();
  for (int off = 128; off; off >>= 1) {
    if (tid < off) sred[tid] += sred[tid + off];
    __syncthreads();
  }
  if (tid == 0) s_inv = 1.f / fmaxf(sqrtf(sred[0]), 1e-12f);
  __syncthreads();
  const int lane = tid & 63, wid = tid >> 6;
#pragma unroll
  for (int i = 0; i < 4; ++i) {
    int ch = wid * 4 + i;
    int c = cb * 16 + ch;
    const float* wr = lin_w + (size_t)c * 2048;
    float dotv = 0.f;
#pragma unroll
    for (int j = 0; j < 8; ++j) {
      int idx = j * 64 + lane;
      float4 wv = ((const float4*)wr)[idx];
      const float* ep = &es[idx * 4];
      dotv += wv.x * ep[0] + wv.y * ep[1] + wv.z * ep[2] + wv.w * ep[3];
    }
#pragma unroll
    for (int off = 32; off; off >>= 1) dotv += __shfl_xor(dotv, off);
    if (lane == 0) {
      float z = dotv * s_inv + lin_b[c];
      gs[ch] = 1.f / (1.f + __expf(-z));
    }
  }
  __syncthreads();
  const float* xb = x + ((size_t)b * 512 + cb * 16) * 4096;
  float* ob = out + ((size_t)b * 512 + cb * 16) * 4096;
#pragma unroll
  for (int ch = 0; ch < 16; ++ch) {
    float g = gs[ch];
    int i = nq * 256 + tid;           // one float4 per thread per channel quarter
    float4 v = ((const float4*)(xb + ch * 4096))[i];
    v.x *= g; v.y *= g; v.z *= g; v.w *= g;
    ((float4*)(ob + ch * 4096))[i] = v;
  }
}

extern "C" void kernel_launch(void* const* d_in, const int* in_sizes, int n_in,
                              void* d_out, int out_size, void* d_ws, size_t ws_size,
                              hipStream_t stream) {
  const float* x      = (const float*)d_in[0];
  const float* conv_w = (const float*)d_in[1];
  const float* conv_b = (const float*)d_in[2];
  const float* bn_g   = (const float*)d_in[3];
  const float* bn_b   = (const float*)d_in[4];
  const float* cw     = (const float*)d_in[5];
  const float* scale  = (const float*)d_in[6];
  const float* lin_w  = (const float*)d_in[7];
  const float* lin_b  = (const float*)d_in[8];
  float* out = (float*)d_out;
  float* ws  = (float*)d_ws;

  unsigned short* y = (unsigned short*)ws;            // [0, 4194304) floats
  float* S0     = ws + 4194304;                       // 256 (S0 | bn_acc contiguous)
  float* bn_acc = ws + 4194560;                       // 256
  float* e_acc  = ws + 4194816;                       // 32768
  unsigned short* w_bf = (unsigned short*)(ws + 4227584);   // 65536 ushorts

  prep<<<64, 256, 0, stream>>>(conv_w, w_bf, S0, e_acc);
  conv_mfma<<<dim3(64, 16), 256, 0, stream>>>(x, w_bf, conv_b, y, bn_acc);
  encode<<<dim3(32, 16), 128, 0, stream>>>(y, bn_acc, bn_g, bn_b, cw, scale, e_acc, S0);
  gscale<<<dim3(128, 16), 256, 0, stream>>>(e_acc, S0, cw, lin_w, lin_b, x, out);
}